// Round 1
// baseline (1132.045 us; speedup 1.0000x reference)
//
#include <hip/hip_runtime.h>
#include <hip/hip_bf16.h>
#include <cstdint>

typedef __attribute__((ext_vector_type(8))) short short8;
typedef __attribute__((ext_vector_type(4))) float floatx4;

#define Bdim 32
#define Tdim 48
#define Ldim 400
#define Hdim 512
#define Edim 128
#define Vdim 50000
#define VEdim 50100
#define BTdim 1536
#define CATdim 1536
#define NCHUNK 782     // ceil(50000/64)
#define NPAD 50048     // NCHUNK*64
#define MTILES 96      // BTdim/16

__device__ __forceinline__ short f2bf(float x){
    __hip_bfloat16 h = __float2bfloat16(x);
    union { __hip_bfloat16 h; short s; } u; u.h = h; return u.s;
}

// ---------------- fp32 tiled GEMM, C = A(MxK) @ B(KxN), row-major ----------
__global__ __launch_bounds__(256) void sgemm_nn(
    const float* __restrict__ A, int lda, long sA,
    const float* __restrict__ B, int ldb, long sB,
    float* __restrict__ C, int ldc, long sC,
    int M, int N, int K)
{
    A += (size_t)blockIdx.z * sA;
    B += (size_t)blockIdx.z * sB;
    C += (size_t)blockIdx.z * sC;
    const int m0 = blockIdx.y * 64, n0 = blockIdx.x * 64;
    __shared__ float As[16][68];
    __shared__ float Bs[16][68];
    const int tid = threadIdx.x;
    const int tx = tid & 15, ty = tid >> 4;
    float acc[4][4] = {};
    for (int k0 = 0; k0 < K; k0 += 16){
        {
            int r = tid >> 2, c = (tid & 3) * 4;
            float4 v = make_float4(0.f,0.f,0.f,0.f);
            if (m0 + r < M) v = *(const float4*)(A + (size_t)(m0+r)*lda + k0 + c);
            As[c+0][r]=v.x; As[c+1][r]=v.y; As[c+2][r]=v.z; As[c+3][r]=v.w;
        }
        {
            int r = tid >> 4, c = (tid & 15) * 4;
            float4 v = make_float4(0.f,0.f,0.f,0.f);
            if (n0 + c < N) v = *(const float4*)(B + (size_t)(k0+r)*ldb + n0 + c);
            Bs[r][c+0]=v.x; Bs[r][c+1]=v.y; Bs[r][c+2]=v.z; Bs[r][c+3]=v.w;
        }
        __syncthreads();
        #pragma unroll
        for (int k=0;k<16;k++){
            float a[4], b[4];
            #pragma unroll
            for (int i=0;i<4;i++) a[i] = As[k][ty*4+i];
            #pragma unroll
            for (int j=0;j<4;j++) b[j] = Bs[k][tx*4+j];
            #pragma unroll
            for (int i=0;i<4;i++)
                #pragma unroll
                for (int j=0;j<4;j++)
                    acc[i][j] += a[i]*b[j];
        }
        __syncthreads();
    }
    #pragma unroll
    for (int i=0;i<4;i++){
        int m = m0 + ty*4 + i;
        if (m >= M) continue;
        #pragma unroll
        for (int j=0;j<4;j++){
            int n = n0 + tx*4 + j;
            if (n < N) C[(size_t)m*ldc + n] = acc[i][j];
        }
    }
}

// ---------------- fp32 tiled GEMM, C = A(MxK) @ B(NxK)^T ------------------
__global__ __launch_bounds__(256) void sgemm_nt(
    const float* __restrict__ A, int lda, long sA,
    const float* __restrict__ B, int ldb, long sB,
    float* __restrict__ C, int ldc, long sC,
    int M, int N, int K)
{
    A += (size_t)blockIdx.z * sA;
    B += (size_t)blockIdx.z * sB;
    C += (size_t)blockIdx.z * sC;
    const int m0 = blockIdx.y * 64, n0 = blockIdx.x * 64;
    __shared__ float As[16][68];
    __shared__ float Bs[16][68];
    const int tid = threadIdx.x;
    const int tx = tid & 15, ty = tid >> 4;
    float acc[4][4] = {};
    for (int k0 = 0; k0 < K; k0 += 16){
        {
            int r = tid >> 2, c = (tid & 3) * 4;
            float4 v = make_float4(0.f,0.f,0.f,0.f);
            if (m0 + r < M) v = *(const float4*)(A + (size_t)(m0+r)*lda + k0 + c);
            As[c+0][r]=v.x; As[c+1][r]=v.y; As[c+2][r]=v.z; As[c+3][r]=v.w;
        }
        {
            int r = tid >> 2, c = (tid & 3) * 4;
            float4 v = make_float4(0.f,0.f,0.f,0.f);
            if (n0 + r < N) v = *(const float4*)(B + (size_t)(n0+r)*ldb + k0 + c);
            Bs[c+0][r]=v.x; Bs[c+1][r]=v.y; Bs[c+2][r]=v.z; Bs[c+3][r]=v.w;
        }
        __syncthreads();
        #pragma unroll
        for (int k=0;k<16;k++){
            float a[4], b[4];
            #pragma unroll
            for (int i=0;i<4;i++) a[i] = As[k][ty*4+i];
            #pragma unroll
            for (int j=0;j<4;j++) b[j] = Bs[k][tx*4+j];
            #pragma unroll
            for (int i=0;i<4;i++)
                #pragma unroll
                for (int j=0;j<4;j++)
                    acc[i][j] += a[i]*b[j];
        }
        __syncthreads();
    }
    #pragma unroll
    for (int i=0;i<4;i++){
        int m = m0 + ty*4 + i;
        if (m >= M) continue;
        #pragma unroll
        for (int j=0;j<4;j++){
            int n = n0 + tx*4 + j;
            if (n < N) C[(size_t)m*ldc + n] = acc[i][j];
        }
    }
}

// ------------- intra-temporal attention prefix scan over t -----------------
__global__ void k_temporal(const float* __restrict__ e, float* __restrict__ att){
    int idx = blockIdx.x * 256 + threadIdx.x;
    if (idx >= Bdim * Ldim) return;
    int b = idx / Ldim, l = idx % Ldim;
    const float* ep = e + (size_t)b * Tdim * Ldim + l;
    float* ap = att + (size_t)b * Tdim * Ldim + l;
    float acc = 0.f;
    for (int t = 0; t < Tdim; ++t){
        float x = __expf(ep[(size_t)t * Ldim]);
        float d = (t == 0) ? 1.f : acc;
        ap[(size_t)t * Ldim] = x / d;
        acc += x;
    }
}

// ------------- normalize temporal over l (in place) ------------------------
__global__ __launch_bounds__(256) void k_attnorm(float* __restrict__ att){
    int row = blockIdx.x;  // b*T + t
    float* ap = att + (size_t)row * Ldim;
    float s = 0.f;
    for (int i = threadIdx.x; i < Ldim; i += 256) s += ap[i];
    #pragma unroll
    for (int off = 32; off; off >>= 1) s += __shfl_down(s, off, 64);
    __shared__ float red[4];
    if ((threadIdx.x & 63) == 0) red[threadIdx.x >> 6] = s;
    __syncthreads();
    float inv = 1.f / (red[0] + red[1] + red[2] + red[3]);
    for (int i = threadIdx.x; i < Ldim; i += 256) ap[i] *= inv;
}

// ------------- masked decoder softmax (rows independent) -------------------
__global__ void k_decsm(float* __restrict__ sbuf){
    int b = blockIdx.x;
    float* sp = sbuf + (size_t)b * Tdim * Tdim;
    int t = threadIdx.x;
    if (t >= Tdim) return;
    float* row = sp + (size_t)t * Tdim;
    if (t == 0){
        for (int j = 0; j < Tdim; ++j) row[j] = 0.f;  // dec_ctx forced 0 at t=0
        return;
    }
    float mx = -1e30f;
    for (int j = 0; j < t; ++j) mx = fmaxf(mx, row[j]);
    float sum = 0.f;
    for (int j = 0; j < t; ++j){ float ex = __expf(row[j]-mx); row[j]=ex; sum+=ex; }
    float inv = 1.f/sum;
    for (int j = 0; j < t; ++j) row[j] *= inv;
    for (int j = t; j < Tdim; ++j) row[j] = 0.f;
}

// ------------- copy h into cat[:, 0:512] -----------------------------------
__global__ void k_copyh(const float* __restrict__ dec, float* __restrict__ cat){
    int idx = blockIdx.x*256 + threadIdx.x;
    if (idx >= BTdim*Hdim) return;
    int m = idx / Hdim, j = idx % Hdim;
    cat[(size_t)m*CATdim + j] = dec[idx];
}

// ------------- pointer gate ------------------------------------------------
__global__ __launch_bounds__(256) void k_pgate(const float* __restrict__ cat,
    const float* __restrict__ wp, const float* __restrict__ bp, float* __restrict__ pg){
    int m = blockIdx.x;
    const float* cp = cat + (size_t)m*CATdim;
    float s = 0.f;
    for (int i=threadIdx.x;i<CATdim;i+=256) s += cp[i]*wp[i];
    #pragma unroll
    for (int off=32; off; off>>=1) s += __shfl_down(s, off, 64);
    __shared__ float red[4];
    if ((threadIdx.x&63)==0) red[threadIdx.x>>6]=s;
    __syncthreads();
    if (threadIdx.x==0){
        float tot = red[0]+red[1]+red[2]+red[3] + bp[0];
        pg[m] = 1.f/(1.f + __expf(-tot));
    }
}

// ------------- proj fp32 -> bf16 -------------------------------------------
__global__ void k_cvtproj(const float* __restrict__ pf, short* __restrict__ pb){
    int i = blockIdx.x*256 + threadIdx.x;
    if (i < BTdim*Edim) pb[i] = f2bf(pf[i]);
}

// ------------- W_vocab (128 x 50000) -> bf16 transposed (50048 x 128) ------
__global__ __launch_bounds__(256) void k_transw(const float* __restrict__ Wv, short* __restrict__ Wt){
    __shared__ float tile[32][33];
    int n0 = blockIdx.x*32, k0 = blockIdx.y*32;
    int x = threadIdx.x & 31, y0 = threadIdx.x >> 5;  // 32 x 8
    for (int yy=y0; yy<32; yy+=8){
        int n = n0 + x;
        tile[yy][x] = (n < Vdim) ? Wv[(size_t)(k0+yy)*Vdim + n] : 0.f;
    }
    __syncthreads();
    for (int yy=y0; yy<32; yy+=8){
        int n = n0 + yy;
        if (n < NPAD) Wt[(size_t)n*Edim + k0 + x] = f2bf(tile[x][yy]);
    }
}

// ------------- logits pass 1: per-row sum(exp) partials --------------------
__global__ __launch_bounds__(256) void k_logits1(
    const short* __restrict__ Ab, const short* __restrict__ Bt,
    float* __restrict__ partial)
{
    const int lane = threadIdx.x & 63;
    const int wave = threadIdx.x >> 6;
    const int l15 = lane & 15, quad = lane >> 4;
    const int n0 = blockIdx.x*64 + wave*16;
    short8 bfrag[4];
    const short* bp = Bt + (size_t)(n0 + l15)*Edim + quad*8;
    #pragma unroll
    for (int kk=0;kk<4;kk++) bfrag[kk] = *(const short8*)(bp + kk*32);
    const bool valid = (n0 + l15) < Vdim;
    __shared__ float psum[16];
    for (int mt=0; mt<MTILES; ++mt){
        floatx4 acc = {0.f,0.f,0.f,0.f};
        const short* ap = Ab + (size_t)(mt*16 + l15)*Edim + quad*8;
        #pragma unroll
        for (int kk=0;kk<4;kk++){
            short8 af = *(const short8*)(ap + kk*32);
            acc = __builtin_amdgcn_mfma_f32_16x16x32_bf16(af, bfrag[kk], acc, 0, 0, 0);
        }
        float ex0 = valid ? __expf(acc[0]) : 0.f;
        float ex1 = valid ? __expf(acc[1]) : 0.f;
        float ex2 = valid ? __expf(acc[2]) : 0.f;
        float ex3 = valid ? __expf(acc[3]) : 0.f;
        #pragma unroll
        for (int off=1; off<16; off<<=1){
            ex0 += __shfl_xor(ex0, off, 64);
            ex1 += __shfl_xor(ex1, off, 64);
            ex2 += __shfl_xor(ex2, off, 64);
            ex3 += __shfl_xor(ex3, off, 64);
        }
        if (threadIdx.x < 16) psum[threadIdx.x] = 0.f;
        __syncthreads();
        if (l15 < 4){
            float v = (l15==0)?ex0:((l15==1)?ex1:((l15==2)?ex2:ex3));
            atomicAdd(&psum[quad*4 + l15], v);
        }
        __syncthreads();
        if (threadIdx.x < 16)
            partial[(size_t)blockIdx.x*BTdim + mt*16 + threadIdx.x] = psum[threadIdx.x];
        __syncthreads();
    }
}

// ------------- reduce partials -> scale = (1-p)/S --------------------------
__global__ void k_reduce(const float* __restrict__ partial, const float* __restrict__ pg,
                         float* __restrict__ scale){
    int m = blockIdx.x*256 + threadIdx.x;
    if (m >= BTdim) return;
    float s = 0.f;
    for (int c=0;c<NCHUNK;c++) s += partial[(size_t)c*BTdim + m];
    scale[m] = (1.f - pg[m]) / s;
}

// ------------- logits pass 2: write (1-p)*softmax --------------------------
__global__ __launch_bounds__(256) void k_logits2(
    const short* __restrict__ Ab, const short* __restrict__ Bt,
    const float* __restrict__ scale, float* __restrict__ out)
{
    const int lane = threadIdx.x & 63;
    const int wave = threadIdx.x >> 6;
    const int l15 = lane & 15, quad = lane >> 4;
    const int n0 = blockIdx.x*64 + wave*16;
    short8 bfrag[4];
    const short* bp = Bt + (size_t)(n0 + l15)*Edim + quad*8;
    #pragma unroll
    for (int kk=0;kk<4;kk++) bfrag[kk] = *(const short8*)(bp + kk*32);
    const int n = n0 + l15;
    const bool valid = n < Vdim;
    for (int mt=0; mt<MTILES; ++mt){
        floatx4 acc = {0.f,0.f,0.f,0.f};
        const short* ap = Ab + (size_t)(mt*16 + l15)*Edim + quad*8;
        #pragma unroll
        for (int kk=0;kk<4;kk++){
            short8 af = *(const short8*)(ap + kk*32);
            acc = __builtin_amdgcn_mfma_f32_16x16x32_bf16(af, bfrag[kk], acc, 0, 0, 0);
        }
        if (valid){
            int m = mt*16 + quad*4;
            out[(size_t)(m+0)*VEdim + n] = scale[m+0]*__expf(acc[0]);
            out[(size_t)(m+1)*VEdim + n] = scale[m+1]*__expf(acc[1]);
            out[(size_t)(m+2)*VEdim + n] = scale[m+2]*__expf(acc[2]);
            out[(size_t)(m+3)*VEdim + n] = scale[m+3]*__expf(acc[3]);
        }
    }
}

// ------------- zero OOV region ---------------------------------------------
__global__ void k_zerooov(float* __restrict__ out){
    int i = blockIdx.x*256 + threadIdx.x;
    if (i >= BTdim*100) return;
    int m = i/100, j = i%100;
    out[(size_t)m*VEdim + Vdim + j] = 0.f;
}

// ------------- pointer scatter-add -----------------------------------------
__global__ void k_scatter(const float* __restrict__ att, const float* __restrict__ pg,
                          const int* __restrict__ ev, float* __restrict__ out){
    int idx = blockIdx.x*256 + threadIdx.x;
    if (idx >= BTdim*Ldim) return;
    int m = idx / Ldim, l = idx % Ldim;
    int b = m / Tdim;
    int v = ev[b*Ldim + l];
    atomicAdd(&out[(size_t)m*VEdim + v], pg[m]*att[idx]);
}

extern "C" void kernel_launch(void* const* d_in, const int* in_sizes, int n_in,
                              void* d_out, int out_size, void* d_ws, size_t ws_size,
                              hipStream_t stream)
{
    const float* dec  = (const float*)d_in[0];
    const float* enc  = (const float*)d_in[1];
    const float* Wenc = (const float*)d_in[2];
    const float* Wdec = (const float*)d_in[3];
    const float* Wproj= (const float*)d_in[4];
    const float* Wvoc = (const float*)d_in[5];
    const float* wptr = (const float*)d_in[6];
    const float* bptr = (const float*)d_in[7];
    const int*   ev   = (const int*)d_in[8];
    float* out = (float*)d_out;

    float* ws = (float*)d_ws;
    float* P1      = ws;                       // 1536x512
    float* P2      = P1 + 786432;              // 1536x512
    float* ebuf    = P2 + 786432;              // 32x48x400
    float* att     = ebuf + 614400;            // 32x48x400
    float* sbuf    = att + 614400;             // 32x48x48
    float* cat     = sbuf + 73728;             // 1536x1536
    float* projf   = cat + 2359296;            // 1536x128
    float* pg      = projf + 196608;           // 1536
    float* scale   = pg + 1536;                // 1536
    float* partial = scale + 1536;             // 782x1536
    short* projb   = (short*)(partial + 1201152);  // 1536x128 bf16
    short* Wt      = projb + 196608;               // 50048x128 bf16

    dim3 blk(256);
    // P1 = dec @ W_enc ; P2 = dec @ W_dec
    sgemm_nn<<<dim3(8,24,1), blk, 0, stream>>>(dec, Hdim, 0, Wenc, Hdim, 0, P1, Hdim, 0, BTdim, Hdim, Hdim);
    sgemm_nn<<<dim3(8,24,1), blk, 0, stream>>>(dec, Hdim, 0, Wdec, Hdim, 0, P2, Hdim, 0, BTdim, Hdim, Hdim);
    // e[b] = P1_b (48x512) @ enc_b^T (400x512)
    sgemm_nt<<<dim3(7,1,32), blk, 0, stream>>>(P1, Hdim, (long)Tdim*Hdim, enc, Hdim, (long)Ldim*Hdim,
                                               ebuf, Ldim, (long)Tdim*Ldim, Tdim, Ldim, Hdim);
    // temporal attention prefix scan, then normalize over l
    k_temporal<<<dim3((Bdim*Ldim+255)/256), blk, 0, stream>>>(ebuf, att);
    k_attnorm<<<dim3(BTdim), blk, 0, stream>>>(att);
    // s[b] = P2_b (48x512) @ dec_b^T (48x512); masked softmax
    sgemm_nt<<<dim3(1,1,32), blk, 0, stream>>>(P2, Hdim, (long)Tdim*Hdim, dec, Hdim, (long)Tdim*Hdim,
                                               sbuf, Tdim, (long)Tdim*Tdim, Tdim, Tdim, Hdim);
    k_decsm<<<dim3(Bdim), dim3(64), 0, stream>>>(sbuf);
    // assemble cat = [h | enc_ctx | dec_ctx]
    k_copyh<<<dim3(BTdim*Hdim/256), blk, 0, stream>>>(dec, cat);
    sgemm_nn<<<dim3(8,1,32), blk, 0, stream>>>(att, Ldim, (long)Tdim*Ldim, enc, Hdim, (long)Ldim*Hdim,
                                               cat+Hdim, CATdim, (long)Tdim*CATdim, Tdim, Hdim, Ldim);
    sgemm_nn<<<dim3(8,1,32), blk, 0, stream>>>(sbuf, Tdim, (long)Tdim*Tdim, dec, Hdim, (long)Tdim*Hdim,
                                               cat+2*Hdim, CATdim, (long)Tdim*CATdim, Tdim, Hdim, Tdim);
    // pointer gate and projection
    k_pgate<<<dim3(BTdim), blk, 0, stream>>>(cat, wptr, bptr, pg);
    sgemm_nn<<<dim3(2,24,1), blk, 0, stream>>>(cat, CATdim, 0, Wproj, Edim, 0, projf, Edim, 0, BTdim, Edim, CATdim);
    k_cvtproj<<<dim3((BTdim*Edim+255)/256), blk, 0, stream>>>(projf, projb);
    // vocab GEMM (bf16 MFMA), softmax-fused two-pass
    k_transw<<<dim3(1564,4), blk, 0, stream>>>(Wvoc, Wt);
    k_logits1<<<dim3(NCHUNK), blk, 0, stream>>>(projb, Wt, partial);
    k_reduce<<<dim3((BTdim+255)/256), blk, 0, stream>>>(partial, pg, scale);
    k_logits2<<<dim3(NCHUNK), blk, 0, stream>>>(projb, Wt, scale, out);
    // OOV zeros + pointer scatter
    k_zerooov<<<dim3((BTdim*100+255)/256), blk, 0, stream>>>(out);
    k_scatter<<<dim3((BTdim*Ldim+255)/256), blk, 0, stream>>>(att, pg, ev, out);
}

// Round 2
// 979.821 us; speedup vs baseline: 1.1554x; 1.1554x over previous
//
#include <hip/hip_runtime.h>
#include <hip/hip_bf16.h>
#include <cstdint>

typedef __attribute__((ext_vector_type(8))) short short8;
typedef __attribute__((ext_vector_type(4))) float floatx4;
typedef __attribute__((ext_vector_type(16))) float floatx16;

#define Bdim 32
#define Tdim 48
#define Ldim 400
#define Hdim 512
#define Edim 128
#define Vdim 50000
#define VEdim 50100
#define BTdim 1536
#define CATdim 1536
#define NCHUNK 782     // ceil(50000/64) for pass 1 (64 cols/block)
#define NPAD 50048     // NCHUNK*64; also 391*128 for pass 2
#define MTILES 96      // BTdim/16
#define NPART (NCHUNK*4)   // per-wave partials per row = 3128

__device__ __forceinline__ short f2bf(float x){
    __hip_bfloat16 h = __float2bfloat16(x);
    union { __hip_bfloat16 h; short s; } u; u.h = h; return u.s;
}

// ---------------- fp32 tiled GEMM, C = A(MxK) @ B(KxN), row-major ----------
__global__ __launch_bounds__(256) void sgemm_nn(
    const float* __restrict__ A, int lda, long sA,
    const float* __restrict__ B, int ldb, long sB,
    float* __restrict__ C, int ldc, long sC,
    int M, int N, int K)
{
    A += (size_t)blockIdx.z * sA;
    B += (size_t)blockIdx.z * sB;
    C += (size_t)blockIdx.z * sC;
    const int m0 = blockIdx.y * 64, n0 = blockIdx.x * 64;
    __shared__ float As[16][68];
    __shared__ float Bs[16][68];
    const int tid = threadIdx.x;
    const int tx = tid & 15, ty = tid >> 4;
    float acc[4][4] = {};
    for (int k0 = 0; k0 < K; k0 += 16){
        {
            int r = tid >> 2, c = (tid & 3) * 4;
            float4 v = make_float4(0.f,0.f,0.f,0.f);
            if (m0 + r < M) v = *(const float4*)(A + (size_t)(m0+r)*lda + k0 + c);
            As[c+0][r]=v.x; As[c+1][r]=v.y; As[c+2][r]=v.z; As[c+3][r]=v.w;
        }
        {
            int r = tid >> 4, c = (tid & 15) * 4;
            float4 v = make_float4(0.f,0.f,0.f,0.f);
            if (n0 + c < N) v = *(const float4*)(B + (size_t)(k0+r)*ldb + n0 + c);
            Bs[r][c+0]=v.x; Bs[r][c+1]=v.y; Bs[r][c+2]=v.z; Bs[r][c+3]=v.w;
        }
        __syncthreads();
        #pragma unroll
        for (int k=0;k<16;k++){
            float a[4], b[4];
            #pragma unroll
            for (int i=0;i<4;i++) a[i] = As[k][ty*4+i];
            #pragma unroll
            for (int j=0;j<4;j++) b[j] = Bs[k][tx*4+j];
            #pragma unroll
            for (int i=0;i<4;i++)
                #pragma unroll
                for (int j=0;j<4;j++)
                    acc[i][j] += a[i]*b[j];
        }
        __syncthreads();
    }
    #pragma unroll
    for (int i=0;i<4;i++){
        int m = m0 + ty*4 + i;
        if (m >= M) continue;
        #pragma unroll
        for (int j=0;j<4;j++){
            int n = n0 + tx*4 + j;
            if (n < N) C[(size_t)m*ldc + n] = acc[i][j];
        }
    }
}

// ---------------- fp32 tiled GEMM, C = A(MxK) @ B(NxK)^T ------------------
__global__ __launch_bounds__(256) void sgemm_nt(
    const float* __restrict__ A, int lda, long sA,
    const float* __restrict__ B, int ldb, long sB,
    float* __restrict__ C, int ldc, long sC,
    int M, int N, int K)
{
    A += (size_t)blockIdx.z * sA;
    B += (size_t)blockIdx.z * sB;
    C += (size_t)blockIdx.z * sC;
    const int m0 = blockIdx.y * 64, n0 = blockIdx.x * 64;
    __shared__ float As[16][68];
    __shared__ float Bs[16][68];
    const int tid = threadIdx.x;
    const int tx = tid & 15, ty = tid >> 4;
    float acc[4][4] = {};
    for (int k0 = 0; k0 < K; k0 += 16){
        {
            int r = tid >> 2, c = (tid & 3) * 4;
            float4 v = make_float4(0.f,0.f,0.f,0.f);
            if (m0 + r < M) v = *(const float4*)(A + (size_t)(m0+r)*lda + k0 + c);
            As[c+0][r]=v.x; As[c+1][r]=v.y; As[c+2][r]=v.z; As[c+3][r]=v.w;
        }
        {
            int r = tid >> 2, c = (tid & 3) * 4;
            float4 v = make_float4(0.f,0.f,0.f,0.f);
            if (n0 + r < N) v = *(const float4*)(B + (size_t)(n0+r)*ldb + k0 + c);
            Bs[c+0][r]=v.x; Bs[c+1][r]=v.y; Bs[c+2][r]=v.z; Bs[c+3][r]=v.w;
        }
        __syncthreads();
        #pragma unroll
        for (int k=0;k<16;k++){
            float a[4], b[4];
            #pragma unroll
            for (int i=0;i<4;i++) a[i] = As[k][ty*4+i];
            #pragma unroll
            for (int j=0;j<4;j++) b[j] = Bs[k][tx*4+j];
            #pragma unroll
            for (int i=0;i<4;i++)
                #pragma unroll
                for (int j=0;j<4;j++)
                    acc[i][j] += a[i]*b[j];
        }
        __syncthreads();
    }
    #pragma unroll
    for (int i=0;i<4;i++){
        int m = m0 + ty*4 + i;
        if (m >= M) continue;
        #pragma unroll
        for (int j=0;j<4;j++){
            int n = n0 + tx*4 + j;
            if (n < N) C[(size_t)m*ldc + n] = acc[i][j];
        }
    }
}

// ------------- intra-temporal attention prefix scan over t -----------------
__global__ void k_temporal(const float* __restrict__ e, float* __restrict__ att){
    int idx = blockIdx.x * 256 + threadIdx.x;
    if (idx >= Bdim * Ldim) return;
    int b = idx / Ldim, l = idx % Ldim;
    const float* ep = e + (size_t)b * Tdim * Ldim + l;
    float* ap = att + (size_t)b * Tdim * Ldim + l;
    float acc = 0.f;
    for (int t = 0; t < Tdim; ++t){
        float x = __expf(ep[(size_t)t * Ldim]);
        float d = (t == 0) ? 1.f : acc;
        ap[(size_t)t * Ldim] = x / d;
        acc += x;
    }
}

// ------------- normalize temporal over l (in place) ------------------------
__global__ __launch_bounds__(256) void k_attnorm(float* __restrict__ att){
    int row = blockIdx.x;  // b*T + t
    float* ap = att + (size_t)row * Ldim;
    float s = 0.f;
    for (int i = threadIdx.x; i < Ldim; i += 256) s += ap[i];
    #pragma unroll
    for (int off = 32; off; off >>= 1) s += __shfl_down(s, off, 64);
    __shared__ float red[4];
    if ((threadIdx.x & 63) == 0) red[threadIdx.x >> 6] = s;
    __syncthreads();
    float inv = 1.f / (red[0] + red[1] + red[2] + red[3]);
    for (int i = threadIdx.x; i < Ldim; i += 256) ap[i] *= inv;
}

// ------------- masked decoder softmax (rows independent) -------------------
__global__ void k_decsm(float* __restrict__ sbuf){
    int b = blockIdx.x;
    float* sp = sbuf + (size_t)b * Tdim * Tdim;
    int t = threadIdx.x;
    if (t >= Tdim) return;
    float* row = sp + (size_t)t * Tdim;
    if (t == 0){
        for (int j = 0; j < Tdim; ++j) row[j] = 0.f;  // dec_ctx forced 0 at t=0
        return;
    }
    float mx = -1e30f;
    for (int j = 0; j < t; ++j) mx = fmaxf(mx, row[j]);
    float sum = 0.f;
    for (int j = 0; j < t; ++j){ float ex = __expf(row[j]-mx); row[j]=ex; sum+=ex; }
    float inv = 1.f/sum;
    for (int j = 0; j < t; ++j) row[j] *= inv;
    for (int j = t; j < Tdim; ++j) row[j] = 0.f;
}

// ------------- copy h into cat[:, 0:512] -----------------------------------
__global__ void k_copyh(const float* __restrict__ dec, float* __restrict__ cat){
    int idx = blockIdx.x*256 + threadIdx.x;
    if (idx >= BTdim*Hdim) return;
    int m = idx / Hdim, j = idx % Hdim;
    cat[(size_t)m*CATdim + j] = dec[idx];
}

// ------------- pointer gate ------------------------------------------------
__global__ __launch_bounds__(256) void k_pgate(const float* __restrict__ cat,
    const float* __restrict__ wp, const float* __restrict__ bp, float* __restrict__ pg){
    int m = blockIdx.x;
    const float* cp = cat + (size_t)m*CATdim;
    float s = 0.f;
    for (int i=threadIdx.x;i<CATdim;i+=256) s += cp[i]*wp[i];
    #pragma unroll
    for (int off=32; off; off>>=1) s += __shfl_down(s, off, 64);
    __shared__ float red[4];
    if ((threadIdx.x&63)==0) red[threadIdx.x>>6]=s;
    __syncthreads();
    if (threadIdx.x==0){
        float tot = red[0]+red[1]+red[2]+red[3] + bp[0];
        pg[m] = 1.f/(1.f + __expf(-tot));
    }
}

// ------------- proj split-K partial sum -> bf16 ----------------------------
__global__ void k_cvtproj(const float* __restrict__ pf, short* __restrict__ pb){
    int i = blockIdx.x*256 + threadIdx.x;
    if (i < BTdim*Edim)
        pb[i] = f2bf(pf[i] + pf[i + 196608] + pf[i + 2*196608] + pf[i + 3*196608]);
}

// ------------- W_vocab (128 x 50000) -> bf16 transposed (50048 x 128) ------
__global__ __launch_bounds__(256) void k_transw(const float* __restrict__ Wv, short* __restrict__ Wt){
    __shared__ float tile[32][33];
    int n0 = blockIdx.x*32, k0 = blockIdx.y*32;
    int x = threadIdx.x & 31, y0 = threadIdx.x >> 5;  // 32 x 8
    for (int yy=y0; yy<32; yy+=8){
        int n = n0 + x;
        tile[yy][x] = (n < Vdim) ? Wv[(size_t)(k0+yy)*Vdim + n] : 0.f;
    }
    __syncthreads();
    for (int yy=y0; yy<32; yy+=8){
        int n = n0 + yy;
        if (n < NPAD) Wt[(size_t)n*Edim + k0 + x] = f2bf(tile[x][yy]);
    }
}

// ------------- logits pass 1: per-row sum(exp) per-wave partials -----------
// 16x16x32 MFMA (verified layout). No LDS, no syncthreads: shfl_xor within
// 16-lane col groups, lane l15==0 stores a float4 of 4 row-sums.
__global__ __launch_bounds__(256) void k_logits1(
    const short* __restrict__ Ab, const short* __restrict__ Bt,
    float* __restrict__ partial)
{
    const int lane = threadIdx.x & 63;
    const int wave = threadIdx.x >> 6;
    const int l15 = lane & 15, quad = lane >> 4;
    const int n0 = blockIdx.x*64 + wave*16;
    short8 bfrag[4];
    const short* bp = Bt + (size_t)(n0 + l15)*Edim + quad*8;
    #pragma unroll
    for (int kk=0;kk<4;kk++) bfrag[kk] = *(const short8*)(bp + kk*32);
    const bool valid = (n0 + l15) < Vdim;
    const int wid = blockIdx.x*4 + wave;
    float* pbase = partial + (size_t)wid*BTdim;
    for (int mt=0; mt<MTILES; ++mt){
        floatx4 acc = {0.f,0.f,0.f,0.f};
        const short* ap = Ab + (size_t)(mt*16 + l15)*Edim + quad*8;
        #pragma unroll
        for (int kk=0;kk<4;kk++){
            short8 af = *(const short8*)(ap + kk*32);
            acc = __builtin_amdgcn_mfma_f32_16x16x32_bf16(af, bfrag[kk], acc, 0, 0, 0);
        }
        float ex0 = valid ? __expf(acc[0]) : 0.f;
        float ex1 = valid ? __expf(acc[1]) : 0.f;
        float ex2 = valid ? __expf(acc[2]) : 0.f;
        float ex3 = valid ? __expf(acc[3]) : 0.f;
        #pragma unroll
        for (int off=1; off<16; off<<=1){
            ex0 += __shfl_xor(ex0, off, 64);
            ex1 += __shfl_xor(ex1, off, 64);
            ex2 += __shfl_xor(ex2, off, 64);
            ex3 += __shfl_xor(ex3, off, 64);
        }
        if (l15 == 0){
            float4 v = make_float4(ex0, ex1, ex2, ex3);
            *(float4*)(pbase + mt*16 + quad*4) = v;
        }
    }
}

// ------------- reduce per-wave partials -> scale = (1-p)/S -----------------
__global__ __launch_bounds__(256) void k_reduce(const float* __restrict__ partial,
                         const float* __restrict__ pg, float* __restrict__ scale){
    int m = blockIdx.x;
    float s = 0.f;
    for (int w = threadIdx.x; w < NPART; w += 256)
        s += partial[(size_t)w*BTdim + m];
    #pragma unroll
    for (int off=32; off; off>>=1) s += __shfl_down(s, off, 64);
    __shared__ float red[4];
    if ((threadIdx.x&63)==0) red[threadIdx.x>>6]=s;
    __syncthreads();
    if (threadIdx.x==0)
        scale[m] = (1.f - pg[m]) / (red[0]+red[1]+red[2]+red[3]);
}

// ------------- logits pass 2: write (1-p)*softmax, 32x32x16 MFMA -----------
// C layout: col=lane&31, row=(reg&3)+8*(reg>>2)+4*(lane>>5). Each store instr
// covers two full 128B line segments (32 consecutive lanes per row).
__global__ __launch_bounds__(256) void k_logits2(
    const short* __restrict__ Ab, const short* __restrict__ Bt,
    const float* __restrict__ scale, float* __restrict__ out)
{
    const int lane = threadIdx.x & 63;
    const int wave = threadIdx.x >> 6;
    const int l31 = lane & 31, half = lane >> 5;
    const int n0 = blockIdx.x*128 + wave*32;
    const int n = n0 + l31;
    short8 bfrag[8];
    const short* bp = Bt + (size_t)n*Edim + half*8;
    #pragma unroll
    for (int kk=0;kk<8;kk++) bfrag[kk] = *(const short8*)(bp + kk*16);
    const bool valid = n < Vdim;
    for (int mt=0; mt<48; ++mt){
        floatx16 acc;
        #pragma unroll
        for (int i=0;i<16;i++) acc[i] = 0.f;
        const short* ap = Ab + (size_t)(mt*32 + l31)*Edim + half*8;
        #pragma unroll
        for (int kk=0;kk<8;kk++){
            short8 af = *(const short8*)(ap + kk*16);
            acc = __builtin_amdgcn_mfma_f32_32x32x16_bf16(af, bfrag[kk], acc, 0, 0, 0);
        }
        if (valid){
            #pragma unroll
            for (int r=0;r<16;r++){
                int m = mt*32 + (r&3) + 8*(r>>2) + 4*half;
                out[(size_t)m*VEdim + n] = scale[m]*__expf(acc[r]);
            }
        }
    }
}

// ------------- zero OOV region ---------------------------------------------
__global__ void k_zerooov(float* __restrict__ out){
    int i = blockIdx.x*256 + threadIdx.x;
    if (i >= BTdim*100) return;
    int m = i/100, j = i%100;
    out[(size_t)m*VEdim + Vdim + j] = 0.f;
}

// ------------- pointer scatter-add -----------------------------------------
__global__ void k_scatter(const float* __restrict__ att, const float* __restrict__ pg,
                          const int* __restrict__ ev, float* __restrict__ out){
    int idx = blockIdx.x*256 + threadIdx.x;
    if (idx >= BTdim*Ldim) return;
    int m = idx / Ldim, l = idx % Ldim;
    int b = m / Tdim;
    int v = ev[b*Ldim + l];
    atomicAdd(&out[(size_t)m*VEdim + v], pg[m]*att[idx]);
}

extern "C" void kernel_launch(void* const* d_in, const int* in_sizes, int n_in,
                              void* d_out, int out_size, void* d_ws, size_t ws_size,
                              hipStream_t stream)
{
    const float* dec  = (const float*)d_in[0];
    const float* enc  = (const float*)d_in[1];
    const float* Wenc = (const float*)d_in[2];
    const float* Wdec = (const float*)d_in[3];
    const float* Wproj= (const float*)d_in[4];
    const float* Wvoc = (const float*)d_in[5];
    const float* wptr = (const float*)d_in[6];
    const float* bptr = (const float*)d_in[7];
    const int*   ev   = (const int*)d_in[8];
    float* out = (float*)d_out;

    float* ws = (float*)d_ws;
    float* P1      = ws;                       // 1536x512
    float* P2      = P1 + 786432;              // 1536x512
    float* ebuf    = P2 + 786432;              // 32x48x400
    float* att     = ebuf + 614400;            // 32x48x400
    float* sbuf    = att + 614400;             // 32x48x48
    float* cat     = sbuf + 73728;             // 1536x1536
    float* projf4  = cat + 2359296;            // 4 x 1536x128 (split-K partials)
    float* pg      = projf4 + 4*196608;        // 1536
    float* scale   = pg + 1536;                // 1536
    float* partial = scale + 1536;             // NPART x 1536 = 3128x1536
    short* projb   = (short*)(partial + (size_t)NPART*BTdim);  // 1536x128 bf16
    short* Wt      = projb + 196608;               // 50048x128 bf16

    dim3 blk(256);
    // P1 = dec @ W_enc ; P2 = dec @ W_dec
    sgemm_nn<<<dim3(8,24,1), blk, 0, stream>>>(dec, Hdim, 0, Wenc, Hdim, 0, P1, Hdim, 0, BTdim, Hdim, Hdim);
    sgemm_nn<<<dim3(8,24,1), blk, 0, stream>>>(dec, Hdim, 0, Wdec, Hdim, 0, P2, Hdim, 0, BTdim, Hdim, Hdim);
    // e[b] = P1_b (48x512) @ enc_b^T (400x512)
    sgemm_nt<<<dim3(7,1,32), blk, 0, stream>>>(P1, Hdim, (long)Tdim*Hdim, enc, Hdim, (long)Ldim*Hdim,
                                               ebuf, Ldim, (long)Tdim*Ldim, Tdim, Ldim, Hdim);
    // temporal attention prefix scan, then normalize over l
    k_temporal<<<dim3((Bdim*Ldim+255)/256), blk, 0, stream>>>(ebuf, att);
    k_attnorm<<<dim3(BTdim), blk, 0, stream>>>(att);
    // s[b] = P2_b (48x512) @ dec_b^T (48x512); masked softmax
    sgemm_nt<<<dim3(1,1,32), blk, 0, stream>>>(P2, Hdim, (long)Tdim*Hdim, dec, Hdim, (long)Tdim*Hdim,
                                               sbuf, Tdim, (long)Tdim*Tdim, Tdim, Tdim, Hdim);
    k_decsm<<<dim3(Bdim), dim3(64), 0, stream>>>(sbuf);
    // assemble cat = [h | enc_ctx | dec_ctx]
    k_copyh<<<dim3(BTdim*Hdim/256), blk, 0, stream>>>(dec, cat);
    sgemm_nn<<<dim3(8,1,32), blk, 0, stream>>>(att, Ldim, (long)Tdim*Ldim, enc, Hdim, (long)Ldim*Hdim,
                                               cat+Hdim, CATdim, (long)Tdim*CATdim, Tdim, Hdim, Ldim);
    sgemm_nn<<<dim3(8,1,32), blk, 0, stream>>>(sbuf, Tdim, (long)Tdim*Tdim, dec, Hdim, (long)Tdim*Hdim,
                                               cat+2*Hdim, CATdim, (long)Tdim*CATdim, Tdim, Hdim, Tdim);
    // pointer gate and projection (split-K x4 over blockIdx.z)
    k_pgate<<<dim3(BTdim), blk, 0, stream>>>(cat, wptr, bptr, pg);
    sgemm_nn<<<dim3(2,24,4), blk, 0, stream>>>(cat, CATdim, 384, Wproj, Edim, (long)384*Edim,
                                               projf4, Edim, (long)BTdim*Edim, BTdim, Edim, 384);
    k_cvtproj<<<dim3((BTdim*Edim+255)/256), blk, 0, stream>>>(projf4, projb);
    // vocab GEMM (bf16 MFMA), softmax-fused two-pass
    k_transw<<<dim3(1564,4), blk, 0, stream>>>(Wvoc, Wt);
    k_logits1<<<dim3(NCHUNK), blk, 0, stream>>>(projb, Wt, partial);
    k_reduce<<<dim3(BTdim), blk, 0, stream>>>(partial, pg, scale);
    k_logits2<<<dim3(391), blk, 0, stream>>>(projb, Wt, scale, out);
    // OOV zeros + pointer scatter
    k_zerooov<<<dim3((BTdim*100+255)/256), blk, 0, stream>>>(out);
    k_scatter<<<dim3((BTdim*Ldim+255)/256), blk, 0, stream>>>(att, pg, ev, out);
}